// Round 2
// baseline (275.513 us; speedup 1.0000x reference)
//
#include <hip/hip_runtime.h>
#include <hip/hip_bf16.h>
#include <math.h>

// ---------------------------------------------------------------------------
// WaveletEmbedding: 4-level db4 2D DWT (symmetric) -> detail magnitudes ->
// bilinear upsample -> sigmoid gating.  B=16, C=2, H=W=512, N_SCALES=4.
// Level sizes: 512 -> 259 -> 133 -> 70 -> 38   (n_out = (N+7)>>1)
// ALL I/O IS FLOAT32 (round-1 NaN proved inputs are f32, not bf16).
// ---------------------------------------------------------------------------

#define EPSV 1e-8f

__constant__ float c_lo[8] = {
    -0.010597401784997278f,  0.032883011666982945f,  0.030841381835986965f,
    -0.18703481171888114f,  -0.02798376941698385f,   0.6308807679295904f,
     0.7148465705525415f,    0.23037781330885523f };
// DEC_HI[i] = DEC_LO[7-i] * (i even ? -1 : +1)
__constant__ float c_hi[8] = {
    -0.23037781330885523f,   0.7148465705525415f,   -0.6308807679295904f,
    -0.02798376941698385f,   0.18703481171888114f,   0.030841381835986965f,
    -0.032883011666982945f, -0.010597401784997278f };

__device__ __forceinline__ int symi(int i, int n) {
    // half-sample symmetric extension, single reflection (pad<=7 < n)
    i = (i < 0) ? (-1 - i) : i;
    i = (i >= n) ? (2 * n - 1 - i) : i;
    return i;
}

// ------------------- row DWT: out[k] = sum_j f[j]*x_sym(2k+1-j) ------------
__global__ void row_dwt(const float* __restrict__ in, float* __restrict__ rlo,
                        float* __restrict__ rhi, int Win, int Wout, int total) {
    int idx = blockIdx.x * blockDim.x + threadIdx.x;
    if (idx >= total) return;
    int k  = idx % Wout;
    int rn = idx / Wout;                 // n*H + r  (rows flattened)
    const float* row = in + (size_t)rn * Win;
    float lo = 0.f, hi = 0.f;
    int base = 2 * k + 1;
#pragma unroll
    for (int j = 0; j < 8; ++j) {
        float x = row[symi(base - j, Win)];
        lo += c_lo[j] * x;
        hi += c_hi[j] * x;
    }
    rlo[idx] = lo;
    rhi[idx] = hi;
}

// ------------- column DWT on (rlo,rhi) -> cA (=ll) and magnitude -----------
__global__ void col_dwt(const float* __restrict__ rlo, const float* __restrict__ rhi,
                        float* __restrict__ cA, float* __restrict__ mag,
                        int H, int Wout, int Hout, int total) {
    int idx = blockIdx.x * blockDim.x + threadIdx.x;
    if (idx >= total) return;
    int c    = idx % Wout;
    int rest = idx / Wout;
    int r    = rest % Hout;
    int n    = rest / Hout;
    float ll = 0.f, lh = 0.f, hl = 0.f, hh = 0.f;
    int base = 2 * r + 1;
#pragma unroll
    for (int j = 0; j < 8; ++j) {
        int rr = symi(base - j, H);
        size_t off = ((size_t)n * H + rr) * Wout + c;
        float a = rlo[off];   // row-lowpass
        float b = rhi[off];   // row-highpass
        ll += c_lo[j] * a;    // cA
        lh += c_hi[j] * a;    // LH
        hl += c_lo[j] * b;    // HL
        hh += c_hi[j] * b;    // HH
    }
    cA[idx]  = ll;
    mag[idx] = sqrtf(lh * lh + hl * hl + hh * hh + EPSV);
}

// ------------------- gate: sw[b][s] = sigmoid(t_emb[b] . gate_w[:,s]) ------
__global__ void gate_kernel(const float* __restrict__ t_emb,
                            const float* __restrict__ gate_w,
                            float* __restrict__ sw) {
    int t = threadIdx.x;
    if (t >= 64) return;
    int b = t >> 2, s = t & 3;
    float acc = 0.f;
#pragma unroll 8
    for (int k = 0; k < 64; ++k)
        acc += t_emb[b * 64 + k] * gate_w[k * 4 + s];
    sw[t] = 1.f / (1.f + expf(-acc));
}

// ------------------- bilinear upsample (half-pixel, edge clamp) ------------
__device__ __forceinline__ float bilerp(const float* __restrict__ src, int n,
                                        int i, int j) {
    float scale = (float)n * (1.0f / 512.0f);
    float ui = ((float)i + 0.5f) * scale - 0.5f;
    float uj = ((float)j + 0.5f) * scale - 0.5f;
    float fi0 = floorf(ui), fj0 = floorf(uj);
    float fi = ui - fi0, fj = uj - fj0;
    int i0 = (int)fi0, j0 = (int)fj0;
    int i0c = min(max(i0, 0), n - 1);
    int i1c = min(max(i0 + 1, 0), n - 1);
    int j0c = min(max(j0, 0), n - 1);
    int j1c = min(max(j0 + 1, 0), n - 1);
    const float* r0 = src + (size_t)i0c * n;
    const float* r1 = src + (size_t)i1c * n;
    float v00 = r0[j0c], v01 = r0[j1c];
    float v10 = r1[j0c], v11 = r1[j1c];
    float t0 = v00 + (v01 - v00) * fj;
    float t1 = v10 + (v11 - v10) * fj;
    return t0 + (t1 - t0) * fi;
}

// ------------------- final: upsample + gate + f32 store --------------------
__global__ void final_kernel(const float* __restrict__ cA4, const float* __restrict__ mag4,
                             const float* __restrict__ mag3, const float* __restrict__ mag2,
                             const float* __restrict__ mag1, const float* __restrict__ sw,
                             float* __restrict__ out) {
    int idx = blockIdx.x * blockDim.x + threadIdx.x;
    // total = 16*8*512*512 = 33,554,432 (fits int)
    int j  = idx & 511;
    int i  = (idx >> 9) & 511;
    int ch = (idx >> 18) & 7;
    int b  = idx >> 21;
    int s  = ch & 3;
    int c  = ch >> 2;
    int n  = b * 2 + c;

    float val;
    if (s == 0) {
        const float* a = cA4  + (size_t)n * 38 * 38;
        const float* m = mag4 + (size_t)n * 38 * 38;
        val = 0.5f * (bilerp(a, 38, i, j) + bilerp(m, 38, i, j));
    } else if (s == 1) {
        val = bilerp(mag3 + (size_t)n * 70 * 70, 70, i, j);
    } else if (s == 2) {
        val = bilerp(mag2 + (size_t)n * 133 * 133, 133, i, j);
    } else {
        val = bilerp(mag1 + (size_t)n * 259 * 259, 259, i, j);
    }
    val *= sw[b * 4 + s];
    out[idx] = val;
}

// ---------------------------------------------------------------------------
extern "C" void kernel_launch(void* const* d_in, const int* in_sizes, int n_in,
                              void* d_out, int out_size, void* d_ws, size_t ws_size,
                              hipStream_t stream) {
    (void)in_sizes; (void)n_in; (void)out_size; (void)ws_size;
    const float* image  = (const float*)d_in[0];
    const float* t_emb  = (const float*)d_in[1];
    const float* gate_w = (const float*)d_in[2];
    float* out = (float*)d_out;
    float* ws = (float*)d_ws;

    const int NI = 32;                       // B*C images
    const int S1 = 259 * 259, S2 = 133 * 133, S3 = 70 * 70, S4 = 38 * 38;

    // workspace layout (floats), total ~14.3M floats (~57 MB)
    size_t off = 0;
    float* sw    = ws + off; off += 64;
    float* mag1  = ws + off; off += (size_t)NI * S1;
    float* mag2  = ws + off; off += (size_t)NI * S2;
    float* mag3  = ws + off; off += (size_t)NI * S3;
    float* mag4  = ws + off; off += (size_t)NI * S4;
    float* cA1   = ws + off; off += (size_t)NI * S1;
    float* cA2   = ws + off; off += (size_t)NI * S2;
    float* cA3   = ws + off; off += (size_t)NI * S3;
    float* cA4   = ws + off; off += (size_t)NI * S4;
    float* rowLo = ws + off; off += (size_t)NI * 512 * 259;
    float* rowHi = ws + off; off += (size_t)NI * 512 * 259;

    const int BLK = 256;
    #define GRID(n) (((n) + BLK - 1) / BLK)

    gate_kernel<<<1, 64, 0, stream>>>(t_emb, gate_w, sw);

    // level 1: 512 -> 259
    {
        int tr = NI * 512 * 259;
        row_dwt<<<GRID(tr), BLK, 0, stream>>>(image, rowLo, rowHi, 512, 259, tr);
        int tc = NI * 259 * 259;
        col_dwt<<<GRID(tc), BLK, 0, stream>>>(rowLo, rowHi, cA1, mag1, 512, 259, 259, tc);
    }
    // level 2: 259 -> 133
    {
        int tr = NI * 259 * 133;
        row_dwt<<<GRID(tr), BLK, 0, stream>>>(cA1, rowLo, rowHi, 259, 133, tr);
        int tc = NI * 133 * 133;
        col_dwt<<<GRID(tc), BLK, 0, stream>>>(rowLo, rowHi, cA2, mag2, 259, 133, 133, tc);
    }
    // level 3: 133 -> 70
    {
        int tr = NI * 133 * 70;
        row_dwt<<<GRID(tr), BLK, 0, stream>>>(cA2, rowLo, rowHi, 133, 70, tr);
        int tc = NI * 70 * 70;
        col_dwt<<<GRID(tc), BLK, 0, stream>>>(rowLo, rowHi, cA3, mag3, 133, 70, 70, tc);
    }
    // level 4: 70 -> 38
    {
        int tr = NI * 70 * 38;
        row_dwt<<<GRID(tr), BLK, 0, stream>>>(cA3, rowLo, rowHi, 70, 38, tr);
        int tc = NI * 38 * 38;
        col_dwt<<<GRID(tc), BLK, 0, stream>>>(rowLo, rowHi, cA4, mag4, 70, 38, 38, tc);
    }

    // final: upsample + gate + store (16*8*512*512 threads)
    {
        int total = 16 * 8 * 512 * 512;
        final_kernel<<<GRID(total), BLK, 0, stream>>>(cA4, mag4, mag3, mag2, mag1, sw, out);
    }
    #undef GRID
}